// Round 1
// baseline (80.688 us; speedup 1.0000x reference)
//
#include <hip/hip_runtime.h>

// Problem: z = scatter_ones(zeros[32,6144,350], x[32,200,3]); out = z.reshape(32,-1) @ W + b
// Identity: out[b,o] = sum over UNIQUE flat indices f=(i0*350+i1) in row b of W[f,o] + b[o].
// Only ~200 W rows (5 floats each) are touched per batch row -> pure gather (~128 KB of W).
// Duplicate (i0,i1) within a row counts ONCE (scatter .set semantics) -> dedup required.
//
// R2 changes vs R1 (theory: kernel is latency-bound; shorten the critical path):
//  - dedup via LDS open-addressing hash set (512 slots, atomicCAS, linear probe)
//    instead of O(200^2) wave-uniform LDS scan: ~200 LDS atomics vs ~800 ds_reads
//    on the critical path between the two HBM latency rounds (x-load, W-gather).
//    "CAS winner gathers" is exact under .set-ones semantics (any occurrence wins).
//  - bias prefetched before the gather so its HBM latency hides under the reduce.
//  - flat[] staging array + second __syncthreads removed.

#define B_ROWS 32
#define NHITS  200
#define D1     350
#define OUT_N  5
#define TAB    512     // hash slots; load factor 200/512 ~ 0.39
#define EMPTY  (-1)

__global__ __launch_bounds__(256) void prtnn_gather_kernel(
    const int* __restrict__ x,      // [32,200,3] int32
    const float* __restrict__ W,    // [2150400, 5] f32
    const float* __restrict__ bias, // [5] f32
    float* __restrict__ out)        // [32, 5] f32
{
    const int b    = blockIdx.x;    // one block per batch row
    const int t    = threadIdx.x;
    const int wave = t >> 6;
    const int lane = t & 63;

    __shared__ int   xs[NHITS * 3];   // 600 ints, staged coalesced
    __shared__ int   tab[TAB];        // hash set of flat indices
    __shared__ float wsum[4][OUT_N];

    // init hash table (512 entries, 256 threads x 2) -- before the single barrier
    tab[t]       = EMPTY;
    tab[t + 256] = EMPTY;

    // coalesced stage of this row's indices: 600 ints = 150 int4 (row base 2400B, 16B-aligned)
    const int4* xrow = (const int4*)(x + b * NHITS * 3);
    if (t < 150) ((int4*)xs)[t] = xrow[t];

    // prefetch bias early: its latency hides under hash+gather+reduce
    float bv = 0.f;
    if (t < OUT_N) bv = bias[t];

    __syncthreads();

    float v0 = 0.f, v1 = 0.f, v2 = 0.f, v3 = 0.f, v4 = 0.f;
    if (t < NHITS) {
        // xs reads stride-3 across lanes: gcd(3,32)=1 -> conflict-free
        const int f = xs[3 * t + 1] * D1 + xs[3 * t + 2];

        // insert f into the hash set; exactly one thread per unique f "owns" it
        unsigned slot = ((unsigned)f * 2654435761u) >> 23;  // top 9 bits -> [0,512)
        bool owner = false;
        for (;;) {
            const int prev = atomicCAS(&tab[slot], EMPTY, f);
            if (prev == EMPTY) { owner = true; break; }  // we inserted it
            if (prev == f)     { break; }                // duplicate, someone else owns
            slot = (slot + 1) & (TAB - 1);               // probe next
        }

        if (owner) {
            // 5 independent scalar loads (20B row, only 4B-aligned), all in flight at once
            const float* w = W + (size_t)f * OUT_N;
            v0 = w[0]; v1 = w[1]; v2 = w[2]; v3 = w[3]; v4 = w[4];
        }
    }

    // 64-lane shuffle reduction per output, then per-wave partial to LDS
    float vv[OUT_N] = {v0, v1, v2, v3, v4};
    #pragma unroll
    for (int o = 0; o < OUT_N; ++o) {
        float s = vv[o];
        #pragma unroll
        for (int off = 32; off >= 1; off >>= 1) s += __shfl_down(s, off);
        if (lane == 0) wsum[wave][o] = s;
    }
    __syncthreads();

    if (t < OUT_N) {
        out[b * OUT_N + t] = wsum[0][t] + wsum[1][t] + wsum[2][t] + wsum[3][t] + bv;
    }
}

extern "C" void kernel_launch(void* const* d_in, const int* in_sizes, int n_in,
                              void* d_out, int out_size, void* d_ws, size_t ws_size,
                              hipStream_t stream) {
    const int*   x    = (const int*)d_in[0];     // [32,200,3]
    const float* W    = (const float*)d_in[1];   // [2150400,5]
    const float* bias = (const float*)d_in[2];   // [5]
    float*       out  = (float*)d_out;           // [32,5]

    prtnn_gather_kernel<<<B_ROWS, 256, 0, stream>>>(x, W, bias, out);
}